// Round 2
// baseline (478.533 us; speedup 1.0000x reference)
//
#include <hip/hip_runtime.h>

// UncertaintyDynamicQAgent: 1024-step sequential scan, 8192 independent sessions.
// One thread per session; sel_L/sel_R one-hot -> reductions collapse to selects.
// Latency-bound: 128 waves on 1024 SIMDs, wall time ~ per-step dep chain * 1024.
// R2: named-register double buffer (R1's indexed arrays spilled to scratch:
// VGPR=32, WRITE_SIZE 230MB vs 67MB output).

#define N_TRIALS 1024
#define CH 8                        // steps per chunk
#define NC (N_TRIALS / CH)          // 128 chunks
// per chunk: 6 float4 in (24 floats = 8 steps * 3), 4 float4 out (16 floats)

struct Tables {
    float k0, k1, k2, k3;
    float a00, a01, a02, a03;
    float ga0, ga1, ga2, ga3;
    float gl0, gl1, gl2, gl3;
};

// smooth_clamp(x, 0, 1), beta=100, matches JAX:
// where(x<0.5, sp(x), 1-sp(1-x)), sp(z)=softplus(100z)/100,
// softplus(t)=max(t,0)+log1p(exp(-|t|))
__device__ __forceinline__ float smooth_clamp01(float x) {
    const bool low = x < 0.5f;
    const float y  = low ? x : (1.0f - x);
    const float t  = 100.0f * y;
    const float e  = __expf(-fabsf(t));
    const float l  = __logf(1.0f + e);
    const float sp = (fmaxf(t, 0.0f) + l) * 0.01f;
    return low ? sp : (1.0f - sp);
}

// One scan step. jL = 3 - 2*cl - o (one-hot index of sel_L), jR = jL ^ 2.
// b = (cl==0), a = (o==0). Verified vs reference round 1 (absmax 3.9e-3).
__device__ __forceinline__ void step(bool first, float cl, float o,
                                     float& Q0, float& Q1, float& l0, float& l1,
                                     float& al, const Tables& tb) {
    const bool b = cl < 0.5f;   // chose right
    const bool a = o  < 0.5f;   // no reward

    const float k_lo  = a ? tb.k1  : tb.k0;
    const float k_hi  = a ? tb.k3  : tb.k2;
    const float kL    = b ? k_hi   : k_lo;    // k_vals[jL]
    const float kR    = b ? k_lo   : k_hi;    // k_vals[jR]
    const float gl_lo = a ? tb.gl1 : tb.gl0;
    const float gl_hi = a ? tb.gl3 : tb.gl2;
    const float glL   = b ? gl_hi  : gl_lo;   // gamma_lams[jL]
    const float glR   = b ? gl_lo  : gl_hi;   // gamma_lams[jR]
    const float ga    = b ? (a ? tb.ga3 : tb.ga2) : (a ? tb.ga1 : tb.ga0);
    const float a0i   = a ? tb.a01 : tb.a00;  // alpha0s[1-o]

    const float dL    = kL - Q0;
    const float dR    = kR - Q1;
    const float lamdL = fabsf(dL) - l0;
    const float lamdR = fabsf(dR) - l1;

    float alpha_new;
    if (first) {
        alpha_new = b ? (a ? tb.a03 : tb.a02) : (a ? tb.a01 : tb.a00); // alpha0s[jL]
    } else {
        const float lamd_c = b ? lamdR : lamdL;
        alpha_new = smooth_clamp01(fmaf(ga, (a0i + lamd_c) - al, al));
    }

    const float nl0 = smooth_clamp01(fmaf(glL, lamdL, l0));
    const float nl1 = smooth_clamp01(fmaf(glR, lamdR, l1));
    const float nQ0 = fmaf(alpha_new * (1.0f - l0), dL, Q0);
    const float nQ1 = fmaf(alpha_new * (1.0f - l1), dR, Q1);

    Q0 = nQ0; Q1 = nQ1; l0 = nl0; l1 = nl1; al = alpha_new;
}

extern "C" __global__ void __launch_bounds__(64, 1)
uq_scan_kernel(const float* __restrict__ inp,
               const float* __restrict__ alpha0s,
               const float* __restrict__ gamma_alphas,
               const float* __restrict__ gamma_lams,
               const float* __restrict__ k_vals,
               float* __restrict__ out, int n_sess) {
    const int s = blockIdx.x * blockDim.x + threadIdx.x;
    if (s >= n_sess) return;

    Tables tb;
    tb.k0  = k_vals[0];       tb.k1  = k_vals[1];
    tb.k2  = k_vals[2];       tb.k3  = k_vals[3];
    tb.a00 = alpha0s[0];      tb.a01 = alpha0s[1];
    tb.a02 = alpha0s[2];      tb.a03 = alpha0s[3];
    tb.ga0 = gamma_alphas[0]; tb.ga1 = gamma_alphas[1];
    tb.ga2 = gamma_alphas[2]; tb.ga3 = gamma_alphas[3];
    tb.gl0 = gamma_lams[0];   tb.gl1 = gamma_lams[1];
    tb.gl2 = gamma_lams[2];   tb.gl3 = gamma_lams[3];

    const float4* __restrict__ rp =
        (const float4*)inp + (size_t)s * (N_TRIALS * 3 / 4);   // 768 f4/session
    float4* __restrict__ op =
        (float4*)out + (size_t)s * (N_TRIALS * 2 / 4);          // 512 f4/session

    float Q0 = 0.0f, Q1 = 0.0f, l0 = 0.5f, l1 = 0.5f, al = 0.0f;

    // Named-register double buffer: 6 float4 per 8-step chunk, prefetch depth 1.
    float4 c0 = rp[0], c1 = rp[1], c2 = rp[2], c3 = rp[3], c4 = rp[4], c5 = rp[5];

    for (int c = 0; c < NC; ++c) {
        const int pre = (c + 1 < NC) ? (c + 1) : c;   // last iter: harmless reload
        const float4* __restrict__ pp = rp + (size_t)pre * 6;
        const float4 n0 = pp[0], n1 = pp[1], n2 = pp[2],
                     n3 = pp[3], n4 = pp[4], n5 = pp[5];

        float4* __restrict__ o = op + (size_t)c * 4;
        float qa, qb;

        // steps 0..7: step u reads floats [3u]=cl, [3u+2]=o from c0..c5
        step(c == 0, c0.x, c0.z, Q0, Q1, l0, l1, al, tb);     // u=0
        qa = Q0; qb = Q1;
        step(false, c0.w, c1.y, Q0, Q1, l0, l1, al, tb);      // u=1
        o[0] = make_float4(qa, qb, Q0, Q1);

        step(false, c1.z, c2.x, Q0, Q1, l0, l1, al, tb);      // u=2
        qa = Q0; qb = Q1;
        step(false, c2.y, c2.w, Q0, Q1, l0, l1, al, tb);      // u=3
        o[1] = make_float4(qa, qb, Q0, Q1);

        step(false, c3.x, c3.z, Q0, Q1, l0, l1, al, tb);      // u=4
        qa = Q0; qb = Q1;
        step(false, c3.w, c4.y, Q0, Q1, l0, l1, al, tb);      // u=5
        o[2] = make_float4(qa, qb, Q0, Q1);

        step(false, c4.z, c5.x, Q0, Q1, l0, l1, al, tb);      // u=6
        qa = Q0; qb = Q1;
        step(false, c5.y, c5.w, Q0, Q1, l0, l1, al, tb);      // u=7
        o[3] = make_float4(qa, qb, Q0, Q1);

        c0 = n0; c1 = n1; c2 = n2; c3 = n3; c4 = n4; c5 = n5;
    }
}

extern "C" void kernel_launch(void* const* d_in, const int* in_sizes, int n_in,
                              void* d_out, int out_size, void* d_ws, size_t ws_size,
                              hipStream_t stream) {
    const float* inp = (const float*)d_in[0];
    const float* a0  = (const float*)d_in[1];
    const float* ga  = (const float*)d_in[2];
    const float* gl  = (const float*)d_in[3];
    const float* kv  = (const float*)d_in[4];
    float* out       = (float*)d_out;

    const int n_sess = in_sizes[0] / (N_TRIALS * 3);
    const int block  = 64;   // 1 wave/block -> 128 blocks spread across CUs
    const int grid   = (n_sess + block - 1) / block;
    uq_scan_kernel<<<grid, block, 0, stream>>>(inp, a0, ga, gl, kv, out, n_sess);
}

// Round 3
// 384.571 us; speedup vs baseline: 1.2443x; 1.2443x over previous
//
#include <hip/hip_runtime.h>

// UncertaintyDynamicQAgent: 1024-step sequential scan, 8192 independent sessions.
// One thread per session; sel_L/sel_R one-hot -> reductions collapse to selects.
// Latency-bound: 128 waves on 1024 SIMDs -> wall time ~ per-step dep chain * 1024.
//
// R3: the R1/R2 failures were the compiler's occupancy heuristic sinking all
// prefetch loads to their use sites (VGPR_Count 32/36 despite ~100 regs of
// declared buffering). amdgpu_waves_per_eu(1,1) lifts the register budget to
// the full file (we can never exceed 1 wave/EU: 128 waves on 1024 SIMDs).
// Ping-pong chunk buffers (no rotation copies -> no vmcnt drain at chunk end).

#define N_TRIALS 1024
#define CH 16                       // steps per chunk
#define NC (N_TRIALS / CH)          // 64 chunks (even -> clean ping-pong)

struct Tables {
    float k0, k1, k2, k3;
    float a00, a01, a02, a03;
    float ga0, ga1, ga2, ga3;
    float gl0, gl1, gl2, gl3;
};

// 12 float4 = 48 floats = 16 steps * 3. Named members (no arrays) so SROA
// keeps every field in registers.
struct Chunk {
    float4 f0, f1, f2, f3, f4, f5, f6, f7, f8, f9, f10, f11;
};

__device__ __forceinline__ void load_chunk(Chunk& ch, const float4* __restrict__ p) {
    ch.f0  = p[0];  ch.f1  = p[1];  ch.f2  = p[2];  ch.f3  = p[3];
    ch.f4  = p[4];  ch.f5  = p[5];  ch.f6  = p[6];  ch.f7  = p[7];
    ch.f8  = p[8];  ch.f9  = p[9];  ch.f10 = p[10]; ch.f11 = p[11];
}

// smooth_clamp(x, 0, 1), beta=100, matches JAX:
// where(x<0.5, sp(x), 1-sp(1-x)), sp(z)=softplus(100z)/100,
// softplus(t)=max(t,0)+log1p(exp(-|t|))
__device__ __forceinline__ float smooth_clamp01(float x) {
    const bool low = x < 0.5f;
    const float y  = low ? x : (1.0f - x);
    const float t  = 100.0f * y;
    const float e  = __expf(-fabsf(t));
    const float l  = __logf(1.0f + e);
    const float sp = (fmaxf(t, 0.0f) + l) * 0.01f;
    return low ? sp : (1.0f - sp);
}

// One scan step. jL = 3 - 2*cl - o (one-hot index of sel_L), jR = jL ^ 2.
// b = (cl==0), a = (o==0). Verified vs reference (absmax 3.9e-3, thr 2e-2).
__device__ __forceinline__ void step(bool first, float cl, float o,
                                     float& Q0, float& Q1, float& l0, float& l1,
                                     float& al, const Tables& tb) {
    const bool b = cl < 0.5f;   // chose right
    const bool a = o  < 0.5f;   // no reward

    const float k_lo  = a ? tb.k1  : tb.k0;
    const float k_hi  = a ? tb.k3  : tb.k2;
    const float kL    = b ? k_hi   : k_lo;    // k_vals[jL]
    const float kR    = b ? k_lo   : k_hi;    // k_vals[jR]
    const float gl_lo = a ? tb.gl1 : tb.gl0;
    const float gl_hi = a ? tb.gl3 : tb.gl2;
    const float glL   = b ? gl_hi  : gl_lo;   // gamma_lams[jL]
    const float glR   = b ? gl_lo  : gl_hi;   // gamma_lams[jR]
    const float ga    = b ? (a ? tb.ga3 : tb.ga2) : (a ? tb.ga1 : tb.ga0);
    const float a0i   = a ? tb.a01 : tb.a00;  // alpha0s[1-o]

    const float dL    = kL - Q0;
    const float dR    = kR - Q1;
    const float lamdL = fabsf(dL) - l0;
    const float lamdR = fabsf(dR) - l1;

    float alpha_new;
    if (first) {
        alpha_new = b ? (a ? tb.a03 : tb.a02) : (a ? tb.a01 : tb.a00); // alpha0s[jL]
    } else {
        const float lamd_c = b ? lamdR : lamdL;
        alpha_new = smooth_clamp01(fmaf(ga, (a0i + lamd_c) - al, al));
    }

    const float nl0 = smooth_clamp01(fmaf(glL, lamdL, l0));
    const float nl1 = smooth_clamp01(fmaf(glR, lamdR, l1));
    const float nQ0 = fmaf(alpha_new * (1.0f - l0), dL, Q0);
    const float nQ1 = fmaf(alpha_new * (1.0f - l1), dR, Q1);

    Q0 = nQ0; Q1 = nQ1; l0 = nl0; l1 = nl1; al = alpha_new;
}

// 8 steps from six float4 (step u: cl = float[3u], o = float[3u+2]).
__device__ __forceinline__ void run8(bool first,
                                     const float4& f0, const float4& f1,
                                     const float4& f2, const float4& f3,
                                     const float4& f4, const float4& f5,
                                     float4* __restrict__ o,
                                     float& Q0, float& Q1, float& l0, float& l1,
                                     float& al, const Tables& tb) {
    float qa, qb;
    step(first, f0.x, f0.z, Q0, Q1, l0, l1, al, tb);   // u=0
    qa = Q0; qb = Q1;
    step(false, f0.w, f1.y, Q0, Q1, l0, l1, al, tb);   // u=1
    o[0] = make_float4(qa, qb, Q0, Q1);

    step(false, f1.z, f2.x, Q0, Q1, l0, l1, al, tb);   // u=2
    qa = Q0; qb = Q1;
    step(false, f2.y, f2.w, Q0, Q1, l0, l1, al, tb);   // u=3
    o[1] = make_float4(qa, qb, Q0, Q1);

    step(false, f3.x, f3.z, Q0, Q1, l0, l1, al, tb);   // u=4
    qa = Q0; qb = Q1;
    step(false, f3.w, f4.y, Q0, Q1, l0, l1, al, tb);   // u=5
    o[2] = make_float4(qa, qb, Q0, Q1);

    step(false, f4.z, f5.x, Q0, Q1, l0, l1, al, tb);   // u=6
    qa = Q0; qb = Q1;
    step(false, f5.y, f5.w, Q0, Q1, l0, l1, al, tb);   // u=7
    o[3] = make_float4(qa, qb, Q0, Q1);
}

__device__ __forceinline__ void run_chunk(bool first_chunk, const Chunk& ch,
                                          float4* __restrict__ o,
                                          float& Q0, float& Q1, float& l0,
                                          float& l1, float& al, const Tables& tb) {
    run8(first_chunk, ch.f0, ch.f1, ch.f2, ch.f3, ch.f4, ch.f5,
         o, Q0, Q1, l0, l1, al, tb);
    run8(false, ch.f6, ch.f7, ch.f8, ch.f9, ch.f10, ch.f11,
         o + 4, Q0, Q1, l0, l1, al, tb);
}

extern "C" __global__ void __launch_bounds__(64)
__attribute__((amdgpu_waves_per_eu(1, 1)))
uq_scan_kernel(const float* __restrict__ inp,
               const float* __restrict__ alpha0s,
               const float* __restrict__ gamma_alphas,
               const float* __restrict__ gamma_lams,
               const float* __restrict__ k_vals,
               float* __restrict__ out, int n_sess) {
    const int s = blockIdx.x * blockDim.x + threadIdx.x;
    if (s >= n_sess) return;

    Tables tb;
    tb.k0  = k_vals[0];       tb.k1  = k_vals[1];
    tb.k2  = k_vals[2];       tb.k3  = k_vals[3];
    tb.a00 = alpha0s[0];      tb.a01 = alpha0s[1];
    tb.a02 = alpha0s[2];      tb.a03 = alpha0s[3];
    tb.ga0 = gamma_alphas[0]; tb.ga1 = gamma_alphas[1];
    tb.ga2 = gamma_alphas[2]; tb.ga3 = gamma_alphas[3];
    tb.gl0 = gamma_lams[0];   tb.gl1 = gamma_lams[1];
    tb.gl2 = gamma_lams[2];   tb.gl3 = gamma_lams[3];

    const float4* __restrict__ rp =
        (const float4*)inp + (size_t)s * (N_TRIALS * 3 / 4);   // 768 f4/session
    float4* __restrict__ op =
        (float4*)out + (size_t)s * (N_TRIALS * 2 / 4);          // 512 f4/session

    float Q0 = 0.0f, Q1 = 0.0f, l0 = 0.5f, l1 = 0.5f, al = 0.0f;

    Chunk A, B;
    load_chunk(A, rp);                      // chunk 0

    // Ping-pong: prefetch exactly one chunk ahead; no buffer copies, so the
    // only waits are vmcnt on data issued ~1300 compute-cycles earlier.
    for (int c = 0; c < NC; c += 2) {
        load_chunk(B, rp + (size_t)(c + 1) * 12);               // always < NC
        run_chunk(c == 0, A, op + (size_t)c * 8, Q0, Q1, l0, l1, al, tb);

        const int pre = (c + 2 < NC) ? (c + 2) : (NC - 1);      // clamp: harmless reload
        load_chunk(A, rp + (size_t)pre * 12);
        run_chunk(false, B, op + (size_t)(c + 1) * 8, Q0, Q1, l0, l1, al, tb);
    }
}

extern "C" void kernel_launch(void* const* d_in, const int* in_sizes, int n_in,
                              void* d_out, int out_size, void* d_ws, size_t ws_size,
                              hipStream_t stream) {
    const float* inp = (const float*)d_in[0];
    const float* a0  = (const float*)d_in[1];
    const float* ga  = (const float*)d_in[2];
    const float* gl  = (const float*)d_in[3];
    const float* kv  = (const float*)d_in[4];
    float* out       = (float*)d_out;

    const int n_sess = in_sizes[0] / (N_TRIALS * 3);
    const int block  = 64;   // 1 wave/block -> 128 blocks spread across CUs
    const int grid   = (n_sess + block - 1) / block;
    uq_scan_kernel<<<grid, block, 0, stream>>>(inp, a0, ga, gl, kv, out, n_sess);
}